// Round 1
// baseline (5298.729 us; speedup 1.0000x reference)
//
#include <hip/hip_runtime.h>

// BEiT self-attention: B=64, S=197, D=768, H=12, HD=64
// Pipeline:
//   1. k_convert_h   : hidden fp32 -> bf16, M padded 12608->12672
//   2. k_convert_w   : wq/wk/wv fp32 -> combined bf16 W [2304][768] (row-major [n][k], B^T form)
//   3. k_bias_expand : bias_table[rel_index] -> dense [H][S][S] fp32
//   4. k_gemm_qkv    : bf16 MFMA GEMM [12608x768]x[768x2304], +bias, scatter to Q/K/V [B,H,S,HD] bf16
//   5. k_attn        : per-(b,h) block: K,V in LDS (bf16), fp32 scores+softmax+PV, out fp32

#define S_LEN 197
#define HEADS 12
#define HDIM 64
#define DMODEL 768
#define BATCH 64
#define MROWS (BATCH * S_LEN) /* 12608 */
#define MPAD 12672
#define NCOLS (3 * DMODEL) /* 2304 */
#define KDIM DMODEL
#define QKV_ELEMS ((size_t)BATCH * HEADS * S_LEN * HDIM) /* 9,682,944 */

typedef __attribute__((ext_vector_type(8))) short short8;
typedef __attribute__((ext_vector_type(4))) float floatx4;

__device__ __forceinline__ float bf2f(ushort u) {
  union { unsigned int i; float f; } x;
  x.i = ((unsigned int)u) << 16;
  return x.f;
}
__device__ __forceinline__ ushort f2bf(float f) {
  union { float f; unsigned int i; } x;
  x.f = f;
  unsigned int r = x.i + 0x7fffu + ((x.i >> 16) & 1u); // round-to-nearest-even
  return (ushort)(r >> 16);
}

__global__ void k_convert_h(const float* __restrict__ hs, ushort* __restrict__ hbf) {
  int col = blockIdx.x * 256 + threadIdx.x; // < 768
  int row = blockIdx.y;                     // < MPAD
  float v = (row < MROWS) ? hs[(size_t)row * DMODEL + col] : 0.f;
  hbf[(size_t)row * DMODEL + col] = f2bf(v);
}

__global__ void k_convert_w(const float* __restrict__ wq, const float* __restrict__ wk,
                            const float* __restrict__ wv, ushort* __restrict__ wbf) {
  int col = blockIdx.x * 256 + threadIdx.x; // < 768
  int row = blockIdx.y;                     // < 2304
  const float* src = (row < DMODEL) ? &wq[(size_t)row * DMODEL]
                     : (row < 2 * DMODEL) ? &wk[(size_t)(row - DMODEL) * DMODEL]
                                          : &wv[(size_t)(row - 2 * DMODEL) * DMODEL];
  wbf[(size_t)row * DMODEL + col] = f2bf(src[col]);
}

__global__ void k_bias_expand(const float* __restrict__ bt, const int* __restrict__ ridx,
                              float* __restrict__ biasb) {
  int idx = blockIdx.x * 256 + threadIdx.x;
  if (idx >= HEADS * S_LEN * S_LEN) return;
  int h = idx / (S_LEN * S_LEN);
  int r = idx - h * (S_LEN * S_LEN);
  biasb[idx] = bt[ridx[r] * HEADS + h];
}

// 128x128 tile, BK=32, 4 waves each computing 64x64 via 4x4 mfma_f32_16x16x32_bf16.
// LDS row stride 40 ushorts (32+8 pad) -> conflict-free ds_read_b128 fragment loads.
__global__ __launch_bounds__(256) void k_gemm_qkv(
    const ushort* __restrict__ A, const ushort* __restrict__ W,
    const float* __restrict__ bq, const float* __restrict__ bv,
    ushort* __restrict__ Qb, ushort* __restrict__ Kb, ushort* __restrict__ Vb) {
  __shared__ __align__(16) ushort As[128 * 40];
  __shared__ __align__(16) ushort Bs[128 * 40];
  int tid = threadIdx.x;
  int wave = tid >> 6, lane = tid & 63;
  int quad = lane >> 4, l16 = lane & 15;
  int m0 = blockIdx.y * 128, n0 = blockIdx.x * 128;
  int wm = (wave & 1) * 64, wn = (wave >> 1) * 64;

  floatx4 acc[4][4];
  floatx4 z = {0.f, 0.f, 0.f, 0.f};
#pragma unroll
  for (int i = 0; i < 4; ++i)
#pragma unroll
    for (int j = 0; j < 4; ++j) acc[i][j] = z;

  for (int kb = 0; kb < KDIM; kb += 32) {
    // stage 128x32 bf16 tiles of A and W into LDS; 512 16B-chunks each, 2 per thread
#pragma unroll
    for (int s = 0; s < 2; ++s) {
      int c = tid + s * 256;
      int row = c >> 2;
      int kc = (c & 3) * 8;
      *(uint4*)(&As[row * 40 + kc]) =
          *(const uint4*)(&A[(size_t)(m0 + row) * KDIM + kb + kc]);
      *(uint4*)(&Bs[row * 40 + kc]) =
          *(const uint4*)(&W[(size_t)(n0 + row) * KDIM + kb + kc]);
    }
    __syncthreads();
    short8 af[4], bfr[4];
#pragma unroll
    for (int i = 0; i < 4; ++i) {
      // A-frag: [m = lane&15][k = quad*8 + j], 8 contiguous k -> ds_read_b128
      af[i] = *(const short8*)(&As[(wm + i * 16 + l16) * 40 + quad * 8]);
      // B-frag: [n = lane&15][k = quad*8 + j] from W[n][k] (B^T input)
      bfr[i] = *(const short8*)(&Bs[(wn + i * 16 + l16) * 40 + quad * 8]);
    }
#pragma unroll
    for (int i = 0; i < 4; ++i)
#pragma unroll
      for (int j = 0; j < 4; ++j)
        acc[i][j] = __builtin_amdgcn_mfma_f32_16x16x32_bf16(af[i], bfr[j], acc[i][j], 0, 0, 0);
    __syncthreads();
  }

  // epilogue: C/D layout col = lane&15, row = quad*4 + r. Add bias, scatter to [B,H,S,HD] bf16.
#pragma unroll
  for (int j = 0; j < 4; ++j) {
    int col = n0 + wn + j * 16 + l16; // < 2304
    int which = col / DMODEL;         // 0=q 1=k 2=v
    int rem = col - which * DMODEL;
    int hh = rem >> 6;
    int d = rem & 63;
    float bias = (which == 0) ? bq[col] : ((which == 2) ? bv[col - 2 * DMODEL] : 0.f);
    ushort* dst = (which == 0) ? Qb : ((which == 1) ? Kb : Vb);
#pragma unroll
    for (int i = 0; i < 4; ++i) {
#pragma unroll
      for (int r = 0; r < 4; ++r) {
        int m = m0 + wm + i * 16 + quad * 4 + r;
        if (m < MROWS) {
          int bb = m / S_LEN;
          int ss = m - bb * S_LEN;
          dst[((size_t)(bb * HEADS + hh) * S_LEN + ss) * HDIM + d] =
              f2bf(acc[i][j][r] + bias);
        }
      }
    }
  }
}

// One block per (b,h). K stored [d][key] (stride 256, zero-padded), V stored [key][d], both bf16.
// Each wave: 4 queries per pass, lane=key for scores, lane=d for PV, shfl broadcasts.
__global__ __launch_bounds__(256) void k_attn(
    const ushort* __restrict__ Qb, const ushort* __restrict__ Kb,
    const ushort* __restrict__ Vb, const float* __restrict__ biasb,
    float* __restrict__ out) {
  __shared__ ushort Ks[64 * 256];   // [d][key], keys >=197 are zero
  __shared__ ushort Vs[S_LEN * 64]; // [key][d]
  int bh = blockIdx.x;
  int b = bh / HEADS, h = bh - b * HEADS;
  int tid = threadIdx.x;
  int wave = tid >> 6, lane = tid & 63;
  const ushort* Kg = Kb + (size_t)bh * S_LEN * HDIM;
  const ushort* Vg = Vb + (size_t)bh * S_LEN * HDIM;

  unsigned int* Ks32 = (unsigned int*)Ks;
  for (int i = tid; i < 64 * 128; i += 256) Ks32[i] = 0u;
  __syncthreads();
  for (int idx = tid; idx < S_LEN * HDIM; idx += 256) {
    int key = idx >> 6, d = idx & 63;
    Ks[d * 256 + key] = Kg[idx]; // transposed scatter (one-time; conflicts negligible)
    Vs[idx] = Vg[idx];
  }
  __syncthreads();

  const float* biasH = biasb + (size_t)h * S_LEN * S_LEN;
  const ushort* Qg = Qb + (size_t)bh * S_LEN * HDIM;

  for (int p = 0; p < 13; ++p) {
    int q0 = p * 16 + wave * 4; // wave-uniform
    float qreg[4];
#pragma unroll
    for (int qq = 0; qq < 4; ++qq) {
      int q = q0 + qq;
      qreg[qq] = (q < S_LEN) ? bf2f(Qg[q * HDIM + lane]) : 0.f; // lane = d
    }
    float sc[4][4];
#pragma unroll
    for (int qq = 0; qq < 4; ++qq)
#pragma unroll
      for (int c = 0; c < 4; ++c) sc[qq][c] = 0.f;

    // scores: lane = key (4 chunks of 64), d-loop with q broadcast via shfl
    for (int d = 0; d < 64; ++d) {
      float qd[4];
#pragma unroll
      for (int qq = 0; qq < 4; ++qq) qd[qq] = __shfl(qreg[qq], d);
#pragma unroll
      for (int c = 0; c < 4; ++c) {
        float kv = bf2f(Ks[d * 256 + c * 64 + lane]);
#pragma unroll
        for (int qq = 0; qq < 4; ++qq) sc[qq][c] += qd[qq] * kv;
      }
    }

    float pr[4][4];
#pragma unroll
    for (int qq = 0; qq < 4; ++qq) {
      int q = q0 + qq;
      if (q < S_LEN) { // wave-uniform branch
#pragma unroll
        for (int c = 0; c < 4; ++c) {
          int key = c * 64 + lane;
          sc[qq][c] = (key < S_LEN) ? sc[qq][c] * 0.125f + biasH[q * S_LEN + key] : -1e30f;
        }
        float mx = fmaxf(fmaxf(sc[qq][0], sc[qq][1]), fmaxf(sc[qq][2], sc[qq][3]));
#pragma unroll
        for (int off = 32; off > 0; off >>= 1) mx = fmaxf(mx, __shfl_xor(mx, off));
        float ssum = 0.f;
#pragma unroll
        for (int c = 0; c < 4; ++c) {
          float e = __expf(sc[qq][c] - mx);
          pr[qq][c] = e;
          ssum += e;
        }
#pragma unroll
        for (int off = 32; off > 0; off >>= 1) ssum += __shfl_xor(ssum, off);
        float inv = 1.f / ssum;
#pragma unroll
        for (int c = 0; c < 4; ++c) pr[qq][c] *= inv;
      } else {
#pragma unroll
        for (int c = 0; c < 4; ++c) pr[qq][c] = 0.f;
      }
    }

    // PV: lane = d, p broadcast via shfl
    float ctx[4] = {0.f, 0.f, 0.f, 0.f};
#pragma unroll
    for (int c = 0; c < 4; ++c) {
      int kmax = (c < 3) ? 64 : (S_LEN - 192);
      for (int j = 0; j < kmax; ++j) {
        float vv = bf2f(Vs[(c * 64 + j) * 64 + lane]);
#pragma unroll
        for (int qq = 0; qq < 4; ++qq) {
          float pk = __shfl(pr[qq][c], j);
          ctx[qq] += pk * vv;
        }
      }
    }
#pragma unroll
    for (int qq = 0; qq < 4; ++qq) {
      int q = q0 + qq;
      if (q < S_LEN)
        out[((size_t)b * S_LEN + q) * DMODEL + h * HDIM + lane] = ctx[qq];
    }
  }
}

extern "C" void kernel_launch(void* const* d_in, const int* in_sizes, int n_in,
                              void* d_out, int out_size, void* d_ws, size_t ws_size,
                              hipStream_t stream) {
  const float* hs = (const float*)d_in[0];
  const float* wq = (const float*)d_in[1];
  const float* bq = (const float*)d_in[2];
  const float* wk = (const float*)d_in[3];
  const float* wv = (const float*)d_in[4];
  const float* bv = (const float*)d_in[5];
  const float* bt = (const float*)d_in[6];
  const int* ridx = (const int*)d_in[7];
  float* out = (float*)d_out;

  // workspace layout (~83 MB total)
  ushort* hbf = (ushort*)d_ws;                 // MPAD*768 bf16
  ushort* wbf = hbf + (size_t)MPAD * KDIM;     // 2304*768 bf16
  ushort* Qb = wbf + (size_t)NCOLS * KDIM;     // [B,H,S,HD] bf16
  ushort* Kb = Qb + QKV_ELEMS;
  ushort* Vb = Kb + QKV_ELEMS;
  float* biasb = (float*)(Vb + QKV_ELEMS);     // [H,S,S] fp32

  k_convert_h<<<dim3(3, MPAD), 256, 0, stream>>>(hs, hbf);
  k_convert_w<<<dim3(3, NCOLS), 256, 0, stream>>>(wq, wk, wv, wbf);
  int nb = (HEADS * S_LEN * S_LEN + 255) / 256;
  k_bias_expand<<<nb, 256, 0, stream>>>(bt, ridx, biasb);
  k_gemm_qkv<<<dim3(NCOLS / 128, MPAD / 128), 256, 0, stream>>>(hbf, wbf, bq, bv, Qb, Kb, Vb);
  k_attn<<<BATCH * HEADS, 256, 0, stream>>>(Qb, Kb, Vb, biasb, out);
}

// Round 2
// 251.408 us; speedup vs baseline: 21.0763x; 21.0763x over previous
//
#include <hip/hip_runtime.h>

// BEiT self-attention: B=64, S=197, D=768, H=12, HD=64
// Pipeline:
//   1. k_convert_h   : hidden fp32 -> bf16, M padded 12608->12672
//   2. k_convert_w   : wq/wk/wv fp32 -> combined bf16 W [2304][768] (row-major [n][k], B^T form)
//   3. k_bias_expand : bias_table[rel_index] -> dense [H][S][S] fp32
//   4. k_gemm_qkv    : bf16 MFMA GEMM [12608x768]x[768x2304], +bias, scatter to Q/K/V [B,H,S,HD] bf16
//   5. k_attn_mfma   : per-(b,h) block, MFMA scores + in-register softmax + MFMA PV

#define S_LEN 197
#define HEADS 12
#define HDIM 64
#define DMODEL 768
#define BATCH 64
#define MROWS (BATCH * S_LEN) /* 12608 */
#define MPAD 12672
#define NCOLS (3 * DMODEL) /* 2304 */
#define KDIM DMODEL
#define QKV_ELEMS ((size_t)BATCH * HEADS * S_LEN * HDIM) /* 9,682,944 */

// attention tiling
#define NQT 13          /* ceil(197/16) query tiles */
#define SPAD 208        /* 13*16 keys padded */
#define KS_STRIDE 72    /* 64 + 8 pad (ushorts) */
#define VT_STRIDE 232   /* 224 + 8 pad (ushorts) */
#define PS_STRIDE 232

typedef __attribute__((ext_vector_type(8))) short short8;
typedef __attribute__((ext_vector_type(4))) float floatx4;

__device__ __forceinline__ float bf2f(ushort u) {
  union { unsigned int i; float f; } x;
  x.i = ((unsigned int)u) << 16;
  return x.f;
}
__device__ __forceinline__ ushort f2bf(float f) {
  union { float f; unsigned int i; } x;
  x.f = f;
  unsigned int r = x.i + 0x7fffu + ((x.i >> 16) & 1u); // round-to-nearest-even
  return (ushort)(r >> 16);
}

__global__ void k_convert_h(const float* __restrict__ hs, ushort* __restrict__ hbf) {
  int col = blockIdx.x * 256 + threadIdx.x; // < 768
  int row = blockIdx.y;                     // < MPAD
  float v = (row < MROWS) ? hs[(size_t)row * DMODEL + col] : 0.f;
  hbf[(size_t)row * DMODEL + col] = f2bf(v);
}

__global__ void k_convert_w(const float* __restrict__ wq, const float* __restrict__ wk,
                            const float* __restrict__ wv, ushort* __restrict__ wbf) {
  int col = blockIdx.x * 256 + threadIdx.x; // < 768
  int row = blockIdx.y;                     // < 2304
  const float* src = (row < DMODEL) ? &wq[(size_t)row * DMODEL]
                     : (row < 2 * DMODEL) ? &wk[(size_t)(row - DMODEL) * DMODEL]
                                          : &wv[(size_t)(row - 2 * DMODEL) * DMODEL];
  wbf[(size_t)row * DMODEL + col] = f2bf(src[col]);
}

__global__ void k_bias_expand(const float* __restrict__ bt, const int* __restrict__ ridx,
                              float* __restrict__ biasb) {
  int idx = blockIdx.x * 256 + threadIdx.x;
  if (idx >= HEADS * S_LEN * S_LEN) return;
  int h = idx / (S_LEN * S_LEN);
  int r = idx - h * (S_LEN * S_LEN);
  biasb[idx] = bt[ridx[r] * HEADS + h];
}

// 128x128 tile, BK=32, 4 waves each computing 64x64 via 4x4 mfma_f32_16x16x32_bf16.
__global__ __launch_bounds__(256) void k_gemm_qkv(
    const ushort* __restrict__ A, const ushort* __restrict__ W,
    const float* __restrict__ bq, const float* __restrict__ bv,
    ushort* __restrict__ Qb, ushort* __restrict__ Kb, ushort* __restrict__ Vb) {
  __shared__ __align__(16) ushort As[128 * 40];
  __shared__ __align__(16) ushort Bs[128 * 40];
  int tid = threadIdx.x;
  int wave = tid >> 6, lane = tid & 63;
  int quad = lane >> 4, l16 = lane & 15;
  int m0 = blockIdx.y * 128, n0 = blockIdx.x * 128;
  int wm = (wave & 1) * 64, wn = (wave >> 1) * 64;

  floatx4 acc[4][4];
  floatx4 z = {0.f, 0.f, 0.f, 0.f};
#pragma unroll
  for (int i = 0; i < 4; ++i)
#pragma unroll
    for (int j = 0; j < 4; ++j) acc[i][j] = z;

  for (int kb = 0; kb < KDIM; kb += 32) {
#pragma unroll
    for (int s = 0; s < 2; ++s) {
      int c = tid + s * 256;
      int row = c >> 2;
      int kc = (c & 3) * 8;
      *(uint4*)(&As[row * 40 + kc]) =
          *(const uint4*)(&A[(size_t)(m0 + row) * KDIM + kb + kc]);
      *(uint4*)(&Bs[row * 40 + kc]) =
          *(const uint4*)(&W[(size_t)(n0 + row) * KDIM + kb + kc]);
    }
    __syncthreads();
    short8 af[4], bfr[4];
#pragma unroll
    for (int i = 0; i < 4; ++i) {
      af[i] = *(const short8*)(&As[(wm + i * 16 + l16) * 40 + quad * 8]);
      bfr[i] = *(const short8*)(&Bs[(wn + i * 16 + l16) * 40 + quad * 8]);
    }
#pragma unroll
    for (int i = 0; i < 4; ++i)
#pragma unroll
      for (int j = 0; j < 4; ++j)
        acc[i][j] = __builtin_amdgcn_mfma_f32_16x16x32_bf16(af[i], bfr[j], acc[i][j], 0, 0, 0);
    __syncthreads();
  }

#pragma unroll
  for (int j = 0; j < 4; ++j) {
    int col = n0 + wn + j * 16 + l16; // < 2304
    int which = col / DMODEL;         // 0=q 1=k 2=v
    int rem = col - which * DMODEL;
    int hh = rem >> 6;
    int d = rem & 63;
    float bias = (which == 0) ? bq[col] : ((which == 2) ? bv[col - 2 * DMODEL] : 0.f);
    ushort* dst = (which == 0) ? Qb : ((which == 1) ? Kb : Vb);
#pragma unroll
    for (int i = 0; i < 4; ++i) {
#pragma unroll
      for (int r = 0; r < 4; ++r) {
        int m = m0 + wm + i * 16 + quad * 4 + r;
        if (m < MROWS) {
          int bb = m / S_LEN;
          int ss = m - bb * S_LEN;
          dst[((size_t)(bb * HEADS + hh) * S_LEN + ss) * HDIM + d] =
              f2bf(acc[i][j][r] + bias);
        }
      }
    }
  }
}

// MFMA attention. One block per (b,h), 8 waves (512 threads).
// LDS: Ks [key][d] (stride 72), Vt [d][key] (stride 232), Ps per-wave [16][232].
// Scores C-layout: col(key)=lane&15, row(q)=quad*4+reg. Softmax in-register per row,
// normalization deferred to output (PV row-linear). P through LDS (C-layout -> A-layout).
__global__ __launch_bounds__(512) void k_attn_mfma(
    const ushort* __restrict__ Qb, const ushort* __restrict__ Kb,
    const ushort* __restrict__ Vb, const float* __restrict__ biasb,
    float* __restrict__ out) {
  __shared__ __align__(16) ushort Ks[SPAD * KS_STRIDE];    // 29952 B
  __shared__ __align__(16) ushort Vt[HDIM * VT_STRIDE];    // 29696 B
  __shared__ __align__(16) ushort Ps[8 * 16 * PS_STRIDE];  // 59392 B
  int bh = blockIdx.x;
  int b = bh / HEADS, h = bh - b * HEADS;
  int tid = threadIdx.x;
  int wave = tid >> 6, lane = tid & 63;
  int quad = lane >> 4, l16 = lane & 15;

  // zero all LDS (padding rows/cols MUST be 0.0, not stale garbage/NaN)
  {
    uint4 z4 = {0u, 0u, 0u, 0u};
    for (int i = tid; i < SPAD * KS_STRIDE / 8; i += 512) ((uint4*)Ks)[i] = z4;
    for (int i = tid; i < HDIM * VT_STRIDE / 8; i += 512) ((uint4*)Vt)[i] = z4;
    for (int i = tid; i < 8 * 16 * PS_STRIDE / 8; i += 512) ((uint4*)Ps)[i] = z4;
  }
  __syncthreads();

  const ushort* Kg = Kb + (size_t)bh * S_LEN * HDIM;
  const ushort* Vg = Vb + (size_t)bh * S_LEN * HDIM;
  for (int idx = tid; idx < S_LEN * HDIM; idx += 512) {
    int key = idx >> 6, d = idx & 63;
    Ks[key * KS_STRIDE + d] = Kg[idx];
    Vt[d * VT_STRIDE + key] = Vg[idx]; // transposed scatter, one-time
  }
  __syncthreads();

  const ushort* Qg = Qb + (size_t)bh * S_LEN * HDIM;
  const float* biasH = biasb + (size_t)h * S_LEN * S_LEN;
  ushort* Psw = Ps + wave * 16 * PS_STRIDE;

  for (int qt = wave; qt < NQT; qt += 8) {
    int q0 = qt * 16;
    // Q a-frags from global: A[m=l16][k=quad*8+j], two K=32 halves (d 0..31, 32..63).
    // Rows q0+l16 may reach 207: reads spill into Kb region (allocated right after) - unused.
    short8 qa0 = *(const short8*)&Qg[(q0 + l16) * HDIM + quad * 8];
    short8 qa1 = *(const short8*)&Qg[(q0 + l16) * HDIM + 32 + quad * 8];

    // bias prefetch into registers (unconditional clamped load + select)
    floatx4 brow[NQT];
    int qrow = q0 + quad * 4;
#pragma unroll
    for (int kt = 0; kt < NQT; ++kt) {
      int key = kt * 16 + l16;
      int keyc = (key < S_LEN) ? key : (S_LEN - 1);
#pragma unroll
      for (int r = 0; r < 4; ++r) {
        int q = qrow + r;
        int qc = (q < S_LEN) ? q : (S_LEN - 1);
        float bv = biasH[qc * S_LEN + keyc];
        brow[kt][r] = (q < S_LEN && key < S_LEN) ? bv : -1e30f;
      }
    }

    // scores: sacc[kt] = Q(16xHD) . K(16xHD)^T
    floatx4 sacc[NQT];
    floatx4 zz = {0.f, 0.f, 0.f, 0.f};
#pragma unroll
    for (int kt = 0; kt < NQT; ++kt) sacc[kt] = zz;
#pragma unroll
    for (int kt = 0; kt < NQT; ++kt) {
      short8 kb0 = *(const short8*)&Ks[(kt * 16 + l16) * KS_STRIDE + quad * 8];
      short8 kb1 = *(const short8*)&Ks[(kt * 16 + l16) * KS_STRIDE + 32 + quad * 8];
      sacc[kt] = __builtin_amdgcn_mfma_f32_16x16x32_bf16(qa0, kb0, sacc[kt], 0, 0, 0);
      sacc[kt] = __builtin_amdgcn_mfma_f32_16x16x32_bf16(qa1, kb1, sacc[kt], 0, 0, 0);
    }

    // softmax per row (row = quad*4 + r, cols distributed over l16 lanes x kt)
    float mx[4] = {-3e38f, -3e38f, -3e38f, -3e38f};
#pragma unroll
    for (int kt = 0; kt < NQT; ++kt)
#pragma unroll
      for (int r = 0; r < 4; ++r) {
        float s = sacc[kt][r] * 0.125f + brow[kt][r];
        sacc[kt][r] = s;
        mx[r] = fmaxf(mx[r], s);
      }
#pragma unroll
    for (int r = 0; r < 4; ++r) {
      mx[r] = fmaxf(mx[r], __shfl_xor(mx[r], 1));
      mx[r] = fmaxf(mx[r], __shfl_xor(mx[r], 2));
      mx[r] = fmaxf(mx[r], __shfl_xor(mx[r], 4));
      mx[r] = fmaxf(mx[r], __shfl_xor(mx[r], 8));
    }
    float sum[4] = {0.f, 0.f, 0.f, 0.f};
#pragma unroll
    for (int kt = 0; kt < NQT; ++kt)
#pragma unroll
      for (int r = 0; r < 4; ++r) {
        float e = __expf(sacc[kt][r] - mx[r]);
        sum[r] += e;
        Psw[(quad * 4 + r) * PS_STRIDE + kt * 16 + l16] = f2bf(e); // unnormalized P
      }
#pragma unroll
    for (int r = 0; r < 4; ++r) {
      sum[r] += __shfl_xor(sum[r], 1);
      sum[r] += __shfl_xor(sum[r], 2);
      sum[r] += __shfl_xor(sum[r], 4);
      sum[r] += __shfl_xor(sum[r], 8);
    }
    float inv[4];
#pragma unroll
    for (int r = 0; r < 4; ++r) inv[r] = 1.f / sum[r];

    // PV: O(16xHD) = P(16xSPAD) . V(SPADxHD); A=P from LDS, B=V^T from LDS
    floatx4 oacc[4];
#pragma unroll
    for (int dt = 0; dt < 4; ++dt) oacc[dt] = zz;
#pragma unroll
    for (int kk = 0; kk < 7; ++kk) {
      short8 pa = *(const short8*)&Psw[l16 * PS_STRIDE + kk * 32 + quad * 8];
#pragma unroll
      for (int dt = 0; dt < 4; ++dt) {
        short8 vb = *(const short8*)&Vt[(dt * 16 + l16) * VT_STRIDE + kk * 32 + quad * 8];
        oacc[dt] = __builtin_amdgcn_mfma_f32_16x16x32_bf16(pa, vb, oacc[dt], 0, 0, 0);
      }
    }

    // output: C-layout row=q0+quad*4+r, col=d=dt*16+l16; scale by 1/rowsum
    float* outg = out + (size_t)b * S_LEN * DMODEL + h * HDIM;
#pragma unroll
    for (int dt = 0; dt < 4; ++dt) {
#pragma unroll
      for (int r = 0; r < 4; ++r) {
        int q = q0 + quad * 4 + r;
        if (q < S_LEN)
          outg[(size_t)q * DMODEL + dt * 16 + l16] = oacc[dt][r] * inv[r];
      }
    }
  }
}

extern "C" void kernel_launch(void* const* d_in, const int* in_sizes, int n_in,
                              void* d_out, int out_size, void* d_ws, size_t ws_size,
                              hipStream_t stream) {
  const float* hs = (const float*)d_in[0];
  const float* wq = (const float*)d_in[1];
  const float* bq = (const float*)d_in[2];
  const float* wk = (const float*)d_in[3];
  const float* wv = (const float*)d_in[4];
  const float* bv = (const float*)d_in[5];
  const float* bt = (const float*)d_in[6];
  const int* ridx = (const int*)d_in[7];
  float* out = (float*)d_out;

  // workspace layout (~83 MB total)
  ushort* hbf = (ushort*)d_ws;                 // MPAD*768 bf16
  ushort* wbf = hbf + (size_t)MPAD * KDIM;     // 2304*768 bf16
  ushort* Qb = wbf + (size_t)NCOLS * KDIM;     // [B,H,S,HD] bf16
  ushort* Kb = Qb + QKV_ELEMS;                 // (Qb overrun by <1.5KB lands here - benign)
  ushort* Vb = Kb + QKV_ELEMS;
  float* biasb = (float*)(Vb + QKV_ELEMS);     // [H,S,S] fp32

  k_convert_h<<<dim3(3, MPAD), 256, 0, stream>>>(hs, hbf);
  k_convert_w<<<dim3(3, NCOLS), 256, 0, stream>>>(wq, wk, wv, wbf);
  int nb = (HEADS * S_LEN * S_LEN + 255) / 256;
  k_bias_expand<<<nb, 256, 0, stream>>>(bt, ridx, biasb);
  k_gemm_qkv<<<dim3(NCOLS / 128, MPAD / 128), 256, 0, stream>>>(hbf, wbf, bq, bv, Qb, Kb, Vb);
  k_attn_mfma<<<BATCH * HEADS, 512, 0, stream>>>(Qb, Kb, Vb, biasb, out);
}